// Round 2
// baseline (391.435 us; speedup 1.0000x reference)
//
#include <hip/hip_runtime.h>
#include <hip/hip_bf16.h>

// ---------- constants ----------
#define M_ROWS   11520          // b*n = 2*5760
#define D_IN     512
#define HD       1960
#define HDP      2048           // padded hidden dim (multiple of 128)
#define B2       16
#define NVECS    720            // 20*36
#define LH       20
#define LW       36
#define HH       60
#define WW       108
#define CCH      40             // 1960/49

using bf16x8 = __attribute__((ext_vector_type(8))) short;
using f32x4  = __attribute__((ext_vector_type(4))) float;

__device__ __forceinline__ float bf2f(unsigned short u) {
    unsigned int x = ((unsigned int)u) << 16;
    return __builtin_bit_cast(float, x);
}
__device__ __forceinline__ unsigned short f2bf(float f) {
    unsigned int x = __builtin_bit_cast(unsigned int, f);
    unsigned int r = (x + 0x7fffu + ((x >> 16) & 1u)) >> 16;
    return (unsigned short)r;
}

// ---------- x (f32, M x 512) -> xb (bf16) ----------
__global__ void conv_x(const float* __restrict__ x, unsigned short* __restrict__ xb) {
    int idx = blockIdx.x * 256 + threadIdx.x;   // total M_ROWS*512
    xb[idx] = f2bf(x[idx]);
}

// ---------- W1 (f32, 512x1960) -> W1t (bf16, 2048x512) = W1^T zero-padded ----------
__global__ void pack_w1t(const float* __restrict__ W1,
                         unsigned short* __restrict__ W1t) {
    int idx = blockIdx.x * 256 + threadIdx.x;     // n*512 + k, total 2048*512
    int n = idx >> 9, k = idx & 511;
    W1t[idx] = (n < HD) ? f2bf(W1[k * HD + n]) : (unsigned short)0;
}

// ---------- W2 (f32, 1960x512) -> W2t (bf16, 512x2048) = W2^T zero-padded ----------
__global__ void pack_w2t(const float* __restrict__ W2,
                         unsigned short* __restrict__ W2t) {
    int idx = blockIdx.x * 256 + threadIdx.x;     // n*2048 + k, total 512*2048
    int n = idx >> 11, k = idx & 2047;
    W2t[idx] = (k < HD) ? f2bf(W2[k * 512 + n]) : (unsigned short)0;
}

// ---------- GEMM: C = A(bf16, M x lda) * Bt(bf16, N x ldb)^T + bias(f32) ----------
// wave -> 64x64 output tile via 4x4 grid of 16x16x32 MFMAs; block = 4 waves (2x2) -> 128x128
// OUT_F32: write float32 C, else bf16 C.
template <bool OUT_F32>
__global__ __launch_bounds__(256) void gemm_bt(
    const unsigned short* __restrict__ A,
    const unsigned short* __restrict__ Bt,
    const float* __restrict__ bias, int bias_n,
    void* __restrict__ Cv,
    int lda, int ldb, int ldc, int K, int nbx)
{
    int bid  = blockIdx.x;
    int bx   = bid % nbx;
    int by   = bid / nbx;
    int w    = threadIdx.x >> 6;
    int lane = threadIdx.x & 63;
    int quad = lane >> 4;
    int l16  = lane & 15;

    int row0 = by * 128 + (w >> 1) * 64;
    int col0 = bx * 128 + (w & 1) * 64;

    f32x4 acc[4][4] = {};

    for (int k = 0; k < K; k += 32) {
        bf16x8 a[4], b[4];
#pragma unroll
        for (int i = 0; i < 4; i++)
            a[i] = *(const bf16x8*)(A + (size_t)(row0 + i * 16 + l16) * lda + k + quad * 8);
#pragma unroll
        for (int j = 0; j < 4; j++)
            b[j] = *(const bf16x8*)(Bt + (size_t)(col0 + j * 16 + l16) * ldb + k + quad * 8);
#pragma unroll
        for (int i = 0; i < 4; i++)
#pragma unroll
            for (int j = 0; j < 4; j++)
                acc[i][j] = __builtin_amdgcn_mfma_f32_16x16x32_bf16(a[i], b[j], acc[i][j], 0, 0, 0);
    }

#pragma unroll
    for (int j = 0; j < 4; j++) {
        int col = col0 + j * 16 + l16;
        float bv = (col < bias_n) ? bias[col] : 0.0f;
#pragma unroll
        for (int i = 0; i < 4; i++) {
            int rbase = row0 + i * 16 + quad * 4;
#pragma unroll
            for (int r = 0; r < 4; r++) {
                float v = acc[i][j][r] + bv;
                if (OUT_F32)
                    ((float*)Cv)[(size_t)(rbase + r) * ldc + col] = v;
                else
                    ((unsigned short*)Cv)[(size_t)(rbase + r) * ldc + col] = f2bf(v);
            }
        }
    }
}

// ---------- fold + normalize: h (M x HDP, bf16) -> y (16 x 40 x 60 x 108, bf16) ----------
__global__ void fold_kernel(const unsigned short* __restrict__ h,
                            unsigned short* __restrict__ y) {
    int idx = blockIdx.x * 256 + threadIdx.x;
    if (idx >= B2 * CCH * HH * WW) return;
    int c = idx % WW;
    int t = idx / WW;
    int r = t % HH; t /= HH;
    int cch = t % CCH;
    int b2  = t / CCH;

    int rp = r + 3, cp = c + 3;
    int lh_a[3], k1_a[3], n1 = 0;
    for (int k1 = rp % 3; k1 < 7; k1 += 3) {
        int lh = (rp - k1) / 3;
        if (lh >= 0 && lh < LH) { lh_a[n1] = lh; k1_a[n1] = k1; n1++; }
    }
    int lw_a[3], k2_a[3], n2 = 0;
    for (int k2 = cp % 3; k2 < 7; k2 += 3) {
        int lw = (cp - k2) / 3;
        if (lw >= 0 && lw < LW) { lw_a[n2] = lw; k2_a[n2] = k2; n2++; }
    }

    float s = 0.0f;
    int chb = cch * 49;
    for (int i = 0; i < n1; i++) {
        for (int j = 0; j < n2; j++) {
            int rowh = b2 * NVECS + lh_a[i] * LW + lw_a[j];
            s += bf2f(h[(size_t)rowh * HDP + chb + k1_a[i] * 7 + k2_a[j]]);
        }
    }
    y[idx] = f2bf(s / (float)(n1 * n2));
}

// ---------- unfold + relu: y -> uf (M x HDP, bf16), pad channels zeroed ----------
__global__ void unfold_relu(const unsigned short* __restrict__ y,
                            unsigned short* __restrict__ uf) {
    int idx = blockIdx.x * 256 + threadIdx.x;   // row*HDP + ch, total M_ROWS*HDP
    int ch  = idx & (HDP - 1);
    int row = idx >> 11;
    unsigned short outv = 0;
    if (ch < HD) {
        int b2 = row / NVECS;
        int v  = row % NVECS;
        int lh = v / LW, lw = v % LW;
        int cch = ch / 49;
        int rem = ch % 49;
        int k1 = rem / 7, k2 = rem % 7;
        int r  = 3 * lh + k1 - 3;
        int cc = 3 * lw + k2 - 3;
        if ((unsigned)r < (unsigned)HH && (unsigned)cc < (unsigned)WW) {
            unsigned short yb = y[((size_t)(b2 * CCH + cch) * HH + r) * WW + cc];
            outv = (yb & 0x8000u) ? (unsigned short)0 : yb;   // relu on bf16 bits
        }
    }
    uf[idx] = outv;
}

// ---------- launch ----------
extern "C" void kernel_launch(void* const* d_in, const int* in_sizes, int n_in,
                              void* d_out, int out_size, void* d_ws, size_t ws_size,
                              hipStream_t stream) {
    const float* x  = (const float*)d_in[0];
    const float* W1 = (const float*)d_in[1];
    const float* b1 = (const float*)d_in[2];
    const float* W2 = (const float*)d_in[3];
    const float* b2 = (const float*)d_in[4];
    float* out = (float*)d_out;

    unsigned short* ws   = (unsigned short*)d_ws;
    unsigned short* xb   = ws;                                  // M_ROWS*512 bf16
    unsigned short* h_uf = xb + (size_t)M_ROWS * D_IN;          // M_ROWS*HDP (h, later reused as uf)
    unsigned short* y    = h_uf + (size_t)M_ROWS * HDP;         // 16*40*60*108 = 4147200
    unsigned short* w1t  = y + (size_t)B2 * CCH * HH * WW;      // 2048*512
    unsigned short* w2t  = w1t + (size_t)HDP * D_IN;            // 512*2048

    // convert x to bf16
    hipLaunchKernelGGL(conv_x, dim3((M_ROWS * D_IN) / 256), dim3(256), 0, stream, x, xb);
    // pack transposed, padded bf16 weights
    hipLaunchKernelGGL(pack_w1t, dim3((HDP * D_IN) / 256), dim3(256), 0, stream, W1, w1t);
    hipLaunchKernelGGL(pack_w2t, dim3((D_IN * HDP) / 256), dim3(256), 0, stream, W2, w2t);

    // GEMM1: h = x @ W1 + b1   (M=11520, N=2048, K=512), bf16 out
    hipLaunchKernelGGL((gemm_bt<false>), dim3((M_ROWS / 128) * (HDP / 128)), dim3(256), 0, stream,
                       xb, w1t, b1, HD, (void*)h_uf, D_IN, D_IN, HDP, D_IN, HDP / 128);

    // fold + normalize
    int yelems = B2 * CCH * HH * WW;
    hipLaunchKernelGGL(fold_kernel, dim3((yelems + 255) / 256), dim3(256), 0, stream, h_uf, y);

    // unfold + relu (overwrites h buffer with uf)
    hipLaunchKernelGGL(unfold_relu, dim3((M_ROWS * HDP) / 256), dim3(256), 0, stream, y, h_uf);

    // GEMM2: out = uf @ W2 + b2   (M=11520, N=512, K=2048), f32 out
    hipLaunchKernelGGL((gemm_bt<true>), dim3((M_ROWS / 128) * (D_IN / 128)), dim3(256), 0, stream,
                       h_uf, w2t, b2, D_IN, (void*)out, HDP, HDP, D_IN, HDP, D_IN / 128);
}

// Round 3
// 282.032 us; speedup vs baseline: 1.3879x; 1.3879x over previous
//
#include <hip/hip_runtime.h>
#include <hip/hip_bf16.h>

// ---------- constants ----------
#define M_ROWS   11520          // b*n = 2*5760
#define D_IN     512
#define HD       1960
#define HDP      2048           // padded hidden dim (multiple of 128)
#define B2       16
#define NVECS    720            // 20*36
#define LH       20
#define LW       36
#define HH       60
#define WW       108
#define CCH      40             // 1960/49

using bf16x8 = __attribute__((ext_vector_type(8))) short;
using f32x4  = __attribute__((ext_vector_type(4))) float;
using f4     = __attribute__((ext_vector_type(4))) float;
using su4    = __attribute__((ext_vector_type(4))) unsigned short;

__device__ __forceinline__ float bf2f(unsigned short u) {
    unsigned int x = ((unsigned int)u) << 16;
    return __builtin_bit_cast(float, x);
}
__device__ __forceinline__ unsigned short f2bf(float f) {
    unsigned int x = __builtin_bit_cast(unsigned int, f);
    unsigned int r = (x + 0x7fffu + ((x >> 16) & 1u)) >> 16;
    return (unsigned short)r;
}

// async global->LDS, 16 bytes per lane (global_load_lds_dwordx4)
__device__ __forceinline__ void gl_lds16(const unsigned short* g, unsigned short* l) {
    __builtin_amdgcn_global_load_lds(
        (const __attribute__((address_space(1))) unsigned int*)g,
        (__attribute__((address_space(3))) unsigned int*)l, 16, 0, 0);
}

// ---------- x (f32, M x 512) -> xb (bf16), 4 elems/thread ----------
__global__ void conv_x4(const float* __restrict__ x, unsigned short* __restrict__ xb) {
    int t = blockIdx.x * 256 + threadIdx.x;       // total M_ROWS*512/4
    f4 v = ((const f4*)x)[t];
    su4 o;
    o.x = f2bf(v.x); o.y = f2bf(v.y); o.z = f2bf(v.z); o.w = f2bf(v.w);
    ((su4*)xb)[t] = o;
}

// ---------- W1 (f32, 512x1960) -> W1t (bf16, 2048x512) = W1^T padded; LDS transpose ----------
__global__ void pack_w1t_t(const float* __restrict__ W1, unsigned short* __restrict__ W1t) {
    __shared__ unsigned short tile[32][33];
    int blk = blockIdx.x;                         // 16 k-tiles x 64 n-tiles
    int kt = blk & 15, nt = blk >> 4;
    int k0 = kt * 32, n0 = nt * 32;
    int t = threadIdx.x;
    int tx = t & 31, ty = t >> 5;                 // ty in [0,8)
#pragma unroll
    for (int p = 0; p < 4; p++) {
        int k = k0 + ty + p * 8;                  // k < 512 always
        int n = n0 + tx;
        tile[ty + p * 8][tx] = (n < HD) ? f2bf(W1[k * HD + n]) : (unsigned short)0;
    }
    __syncthreads();
#pragma unroll
    for (int p = 0; p < 4; p++) {
        int n = n0 + ty + p * 8;                  // n < 2048 always
        int k = k0 + tx;
        W1t[n * 512 + k] = tile[tx][ty + p * 8];
    }
}

// ---------- W2 (f32, 1960x512) -> W2t (bf16, 512x2048) = W2^T padded; LDS transpose ----------
__global__ void pack_w2t_t(const float* __restrict__ W2, unsigned short* __restrict__ W2t) {
    __shared__ unsigned short tile[32][33];
    int blk = blockIdx.x;                         // 64 k-tiles x 16 n-tiles
    int kt = blk & 63, nt = blk >> 6;
    int k0 = kt * 32, n0 = nt * 32;
    int t = threadIdx.x;
    int tx = t & 31, ty = t >> 5;
#pragma unroll
    for (int p = 0; p < 4; p++) {
        int k = k0 + ty + p * 8;
        int n = n0 + tx;                          // n < 512 always
        tile[ty + p * 8][tx] = (k < HD) ? f2bf(W2[k * 512 + n]) : (unsigned short)0;
    }
    __syncthreads();
#pragma unroll
    for (int p = 0; p < 4; p++) {
        int n = n0 + ty + p * 8;
        int k = k0 + tx;                          // k < 2048 always
        W2t[n * 2048 + k] = tile[tx][ty + p * 8];
    }
}

// ---------- LDS-staged GEMM: C = A(M x lda) * Bt(N x ldb)^T + bias ----------
// 128x128 block tile, 4 waves (2x2 of 64x64), BK=32, global_load_lds width=16.
template <bool OUT_F32>
__global__ __launch_bounds__(256) void gemm_lds(
    const unsigned short* __restrict__ A,
    const unsigned short* __restrict__ Bt,
    const float* __restrict__ bias, int bias_n,
    void* __restrict__ Cv,
    int lda, int ldb, int ldc, int K, int nbx)
{
    __shared__ unsigned short sA[128 * 32];
    __shared__ unsigned short sB[128 * 32];

    int bid  = blockIdx.x;
    int bx   = bid % nbx;
    int by   = bid / nbx;
    int t    = threadIdx.x;
    int w    = t >> 6;
    int lane = t & 63;
    int quad = lane >> 4;
    int l16  = lane & 15;

    int row0 = by * 128, col0 = bx * 128;
    int wr = (w >> 1) * 64, wc = (w & 1) * 64;

    // staging addresses: thread t covers tile row t/4 (and +64), 8 elems at col (t%4)*8
    const unsigned short* Ag = A  + (size_t)(row0 + (t >> 2)) * lda + (t & 3) * 8;
    const unsigned short* Bg = Bt + (size_t)(col0 + (t >> 2)) * ldb + (t & 3) * 8;
    unsigned short* lA0 = sA + t * 8;
    unsigned short* lA1 = sA + 2048 + t * 8;
    unsigned short* lB0 = sB + t * 8;
    unsigned short* lB1 = sB + 2048 + t * 8;

    f32x4 acc[4][4] = {};

    for (int k0 = 0; k0 < K; k0 += 32) {
        gl_lds16(Ag + k0, lA0);
        gl_lds16(Ag + (size_t)64 * lda + k0, lA1);
        gl_lds16(Bg + k0, lB0);
        gl_lds16(Bg + (size_t)64 * ldb + k0, lB1);
        __syncthreads();   // compiler emits s_waitcnt vmcnt(0) before barrier

        bf16x8 a[4], b[4];
#pragma unroll
        for (int i = 0; i < 4; i++)
            a[i] = *(const bf16x8*)(sA + (wr + i * 16 + l16) * 32 + quad * 8);
#pragma unroll
        for (int j = 0; j < 4; j++)
            b[j] = *(const bf16x8*)(sB + (wc + j * 16 + l16) * 32 + quad * 8);
#pragma unroll
        for (int i = 0; i < 4; i++)
#pragma unroll
            for (int j = 0; j < 4; j++)
                acc[i][j] = __builtin_amdgcn_mfma_f32_16x16x32_bf16(a[i], b[j], acc[i][j], 0, 0, 0);
        __syncthreads();   // all reads done before next stage overwrites
    }

#pragma unroll
    for (int j = 0; j < 4; j++) {
        int col = col0 + wc + j * 16 + l16;
        float bv = (col < bias_n) ? bias[col] : 0.0f;
#pragma unroll
        for (int i = 0; i < 4; i++) {
            int rbase = row0 + wr + i * 16 + quad * 4;
#pragma unroll
            for (int r = 0; r < 4; r++) {
                float v = acc[i][j][r] + bv;
                if (OUT_F32)
                    ((float*)Cv)[(size_t)(rbase + r) * ldc + col] = v;
                else
                    ((unsigned short*)Cv)[(size_t)(rbase + r) * ldc + col] = f2bf(v);
            }
        }
    }
}

// ---------- fold + normalize: h (M x HDP, bf16) -> y (16 x 40 x 60 x 108, bf16) ----------
__global__ void fold_kernel(const unsigned short* __restrict__ h,
                            unsigned short* __restrict__ y) {
    int idx = blockIdx.x * 256 + threadIdx.x;
    if (idx >= B2 * CCH * HH * WW) return;
    int c = idx % WW;
    int t = idx / WW;
    int r = t % HH; t /= HH;
    int cch = t % CCH;
    int b2  = t / CCH;

    int rp = r + 3, cp = c + 3;
    int lh_a[3], k1_a[3], n1 = 0;
    for (int k1 = rp % 3; k1 < 7; k1 += 3) {
        int lh = (rp - k1) / 3;
        if (lh >= 0 && lh < LH) { lh_a[n1] = lh; k1_a[n1] = k1; n1++; }
    }
    int lw_a[3], k2_a[3], n2 = 0;
    for (int k2 = cp % 3; k2 < 7; k2 += 3) {
        int lw = (cp - k2) / 3;
        if (lw >= 0 && lw < LW) { lw_a[n2] = lw; k2_a[n2] = k2; n2++; }
    }

    float s = 0.0f;
    int chb = cch * 49;
    for (int i = 0; i < n1; i++) {
        for (int j = 0; j < n2; j++) {
            int rowh = b2 * NVECS + lh_a[i] * LW + lw_a[j];
            s += bf2f(h[(size_t)rowh * HDP + chb + k1_a[i] * 7 + k2_a[j]]);
        }
    }
    y[idx] = f2bf(s / (float)(n1 * n2));
}

// ---------- unfold + relu, 4 channels/thread: y -> uf (M x HDP, bf16) ----------
__global__ void unfold_relu4(const unsigned short* __restrict__ y,
                             unsigned short* __restrict__ uf) {
    int t = blockIdx.x * 256 + threadIdx.x;       // total M_ROWS*512
    int row = t >> 9;
    int ch0 = (t & 511) << 2;
    int b2 = row / NVECS;
    int v  = row - b2 * NVECS;
    int lh = v / LW;
    int lw = v - lh * LW;
    int rb = 3 * lh - 3, cb = 3 * lw - 3;
    const unsigned short* yb = y + (size_t)b2 * CCH * HH * WW;

    su4 o;
#pragma unroll
    for (int e = 0; e < 4; e++) {
        int ch = ch0 + e;
        unsigned short val = 0;
        if (ch < HD) {
            int cch = ch / 49;
            int rem = ch - cch * 49;
            int k1 = rem / 7;
            int k2 = rem - k1 * 7;
            int r  = rb + k1;
            int cc = cb + k2;
            if ((unsigned)r < (unsigned)HH && (unsigned)cc < (unsigned)WW) {
                unsigned short u = yb[(cch * HH + r) * WW + cc];
                val = (u & 0x8000u) ? (unsigned short)0 : u;
            }
        }
        ((unsigned short*)&o)[e] = val;
    }
    *(su4*)(uf + (size_t)row * HDP + ch0) = o;
}

// ---------- launch ----------
extern "C" void kernel_launch(void* const* d_in, const int* in_sizes, int n_in,
                              void* d_out, int out_size, void* d_ws, size_t ws_size,
                              hipStream_t stream) {
    const float* x  = (const float*)d_in[0];
    const float* W1 = (const float*)d_in[1];
    const float* b1 = (const float*)d_in[2];
    const float* W2 = (const float*)d_in[3];
    const float* b2 = (const float*)d_in[4];
    float* out = (float*)d_out;

    unsigned short* ws   = (unsigned short*)d_ws;
    unsigned short* xb   = ws;                                  // M_ROWS*512
    unsigned short* h_uf = xb + (size_t)M_ROWS * D_IN;          // M_ROWS*HDP
    unsigned short* y    = h_uf + (size_t)M_ROWS * HDP;         // 4147200
    unsigned short* w1t  = y + (size_t)B2 * CCH * HH * WW;      // 2048*512
    unsigned short* w2t  = w1t + (size_t)HDP * D_IN;            // 512*2048

    hipLaunchKernelGGL(conv_x4, dim3(M_ROWS * D_IN / 4 / 256), dim3(256), 0, stream, x, xb);
    hipLaunchKernelGGL(pack_w1t_t, dim3(16 * 64), dim3(256), 0, stream, W1, w1t);
    hipLaunchKernelGGL(pack_w2t_t, dim3(64 * 16), dim3(256), 0, stream, W2, w2t);

    // GEMM1: h = x @ W1 + b1   (M=11520, N=2048, K=512), bf16 out
    hipLaunchKernelGGL((gemm_lds<false>), dim3((M_ROWS / 128) * (HDP / 128)), dim3(256), 0, stream,
                       xb, w1t, b1, HD, (void*)h_uf, D_IN, D_IN, HDP, D_IN, HDP / 128);

    // fold + normalize
    int yelems = B2 * CCH * HH * WW;
    hipLaunchKernelGGL(fold_kernel, dim3((yelems + 255) / 256), dim3(256), 0, stream, h_uf, y);

    // unfold + relu (overwrites h buffer with uf)
    hipLaunchKernelGGL(unfold_relu4, dim3(M_ROWS * 512 / 256), dim3(256), 0, stream, y, h_uf);

    // GEMM2: out = uf @ W2 + b2   (M=11520, N=512, K=2048), f32 out
    hipLaunchKernelGGL((gemm_lds<true>), dim3((M_ROWS / 128) * (D_IN / 128)), dim3(256), 0, stream,
                       h_uf, w2t, b2, D_IN, (void*)out, HDP, HDP, D_IN, HDP, D_IN / 128);
}